// Round 13
// baseline (311.640 us; speedup 1.0000x reference)
//
#include <hip/hip_runtime.h>
#include <math.h>

#define Nn 10000
#define Ee 160000
#define NBb 8
#define Gg 100
#define CSRMAX 230400            // >= Ee + 7*Nn, multiple of 256

// sh record per slot: [0..3]=sh0..3, [4..7]=sh4..7, [8]=sh8, [9]=src bits, [10,11]=0
__device__ __align__(16) float g_shc[(size_t)CSRMAX * 12];
__device__ __align__(16) float g_R[(size_t)CSRMAX * 64];    // [slot][64]
__device__ float g_h[2][Nn * 64];
__device__ float g_h1[Nn * 64];
__device__ float g_hsc[Nn * 64];
__device__ float g_nodeE[2][Nn];   // per-layer node energies (no atomics)
__device__ float g_wpro[64];       // W_prod[1] @ w_ro[1]
__device__ int   g_deg[Nn];
__device__ int   g_offs[Nn + 1];
__device__ int   g_cursor[Nn];
__device__ int2  g_er[CSRMAX];     // per-slot (sender, receiver); .x=-1 for pads
__device__ float g_W1T[64 * NBb];  // W_r1 transposed: [j][k]

__global__ __launch_bounds__(256) void k_zero(float* out, int out_size) {
    int i = blockIdx.x * 256 + threadIdx.x;
    if (i < CSRMAX) g_er[i].x = -1;
    if (i < out_size) out[i] = 0.0f;
    if (i < Nn) { g_deg[i] = 0; g_cursor[i] = 0; }
}

// degree count; block 0 also transposes W_r1 and computes W_prod[1]@w_ro[1]
__global__ __launch_bounds__(256) void k_deg(const int* __restrict__ eidx,
                                             const float* __restrict__ Wr1,
                                             const float* __restrict__ Wprod1,
                                             const float* __restrict__ wro1) {
    int e = blockIdx.x * 256 + threadIdx.x;
    if (e < Ee) atomicAdd(&g_deg[eidx[Ee + e]], 1);
    if (blockIdx.x == 0) {
        for (int i = threadIdx.x; i < 64 * NBb; i += 256) {
            int k = i >> 6, j = i & 63;  // Wr1[k][j]
            g_W1T[j * NBb + k] = Wr1[i];
        }
        if (threadIdx.x < 64) {
            int k = threadIdx.x;
            float s = 0.0f;
#pragma unroll
            for (int c = 0; c < 64; c++) s += Wprod1[k * 64 + c] * wro1[c];
            g_wpro[k] = s;
        }
    }
}

// prefix sum of degrees padded up to multiples of 8
__global__ __launch_bounds__(1024) void k_scan() {
    __shared__ int part[1024];
    int t = threadIdx.x;
    const int CH = (Nn + 1023) / 1024;  // 10
    int st = t * CH;
    int en = st + CH; if (en > Nn) en = Nn;
    int s = 0;
    for (int i = st; i < en; i++) s += (g_deg[i] + 7) & ~7;
    part[t] = s;
    __syncthreads();
    for (int d = 1; d < 1024; d <<= 1) {
        int v = (t >= d) ? part[t - d] : 0;
        __syncthreads();
        part[t] += v;
        __syncthreads();
    }
    int base = (t == 0) ? 0 : part[t - 1];
    for (int i = st; i < en; i++) { g_offs[i] = base; base += (g_deg[i] + 7) & ~7; }
    if (t == 1023) g_offs[Nn] = part[1023];
}

// fill slot records: pack (sender, receiver) so k_edge needs no eidx gather
__global__ __launch_bounds__(256) void k_fill(const int* __restrict__ eidx) {
    int e = blockIdx.x * 256 + threadIdx.x;
    if (e >= Ee) return;
    int snd = eidx[e];
    int r = eidx[Ee + e];
    int p = g_offs[r] + atomicAdd(&g_cursor[r], 1);
    g_er[p] = make_int2(snd, r);
}

// 512-thread blocks, 256 slots each: waves 0-3 compute channels 0-31,
// waves 4-7 channels 32-63 (chalf is WAVE-uniform -> weight reads stay on
// the scalar path; per-LANE nonuniformity was the r11 194us regression).
// 2x waves/CU vs 1-thread/slot; acc halves to 32 regs.
__global__ __launch_bounds__(512) void k_edge(const float* __restrict__ pos,
                                              const float* __restrict__ br1,
                                              const float* __restrict__ Wr2) {
    __shared__ float sT[32][257];
    int t = threadIdx.x;
    int total = g_offs[Nn];
    if (blockIdx.x * 256 >= total) return;
    int slot = t & 255;
    int chalf = t >> 8;                 // wave-uniform
    int s = blockIdx.x * 256 + slot;
    int2 er = g_er[s];
    bool real = (er.x >= 0);
    int snd = real ? er.x : 0;
    int rcv = real ? er.y : 0;

    float vx = pos[3 * rcv + 0] - pos[3 * snd + 0];
    float vy = pos[3 * rcv + 1] - pos[3 * snd + 1];
    float vz = pos[3 * rcv + 2] - pos[3 * snd + 2];
    float r = sqrtf(vx * vx + vy * vy + vz * vz);
    float inv = __builtin_amdgcn_rcpf(fmaxf(r, 1e-9f));
    float x = vx * inv, y = vy * inv, z = vz * inv;
    const float s3 = 1.7320508f;
    if (chalf == 0) {
        float4* shp = (float4*)(g_shc + (size_t)s * 12);
        if (real) {
            shp[0] = make_float4(1.0f, x, y, z);
            shp[1] = make_float4(s3 * x * y, s3 * y * z, 0.5f * (3.0f * z * z - 1.0f), s3 * x * z);
            shp[2] = make_float4(0.5f * s3 * (x * x - y * y), __int_as_float(snd), 0.f, 0.f);
        } else {
            shp[0] = make_float4(0.f, 0.f, 0.f, 0.f);
            shp[1] = make_float4(0.f, 0.f, 0.f, 0.f);
            shp[2] = make_float4(0.f, 0.f, 0.f, 0.f);
        }
    }

    float xx = r * 0.2f;
    float env = 0.0f;
    if (xx < 1.0f) {
        float x2 = xx * xx;
        float x6 = x2 * x2 * x2;
        float x7 = x6 * xx;
        float x8 = x7 * xx;
        env = 1.0f - 28.0f * x6 + 48.0f * x7 - 21.0f * x8;
    }
    const float pref = 0.63245553f;  // sqrt(2/R_MAX)
    const float PI_F = 3.14159265358979f;
    float fac = pref * inv * env;
    float ef[NBb];
#pragma unroll
    for (int k = 0; k < NBb; k++)
        ef[k] = fac * __sinf((float)(k + 1) * PI_F * r * 0.2f);

    float acc[32];
#pragma unroll
    for (int c = 0; c < 32; c++) acc[c] = 0.0f;
    const float* __restrict__ w2base = Wr2 + chalf * 32;   // wave-uniform offset
    for (int j = 0; j < 64; j++) {
        float a = br1[j];
#pragma unroll
        for (int k = 0; k < NBb; k++) a += ef[k] * g_W1T[j * NBb + k];
        a = a * __builtin_amdgcn_rcpf(1.0f + __expf(-a));
        const float* __restrict__ w2 = w2base + j * 64;
#pragma unroll
        for (int c = 0; c < 32; c++) acc[c] += a * w2[c];
    }

    size_t base = (size_t)blockIdx.x * 256;
#pragma unroll
    for (int chunk = 0; chunk < 2; chunk++) {
        if (chalf == chunk) {
#pragma unroll
            for (int c = 0; c < 32; c++) sT[c][slot] = real ? acc[c] : 0.0f;
        }
        __syncthreads();
#pragma unroll
        for (int it = 0; it < 4; it++) {
            int idx = it * 512 + t;
            int ss = idx >> 3, c4 = idx & 7;
            float4 v = make_float4(sT[c4 * 4 + 0][ss], sT[c4 * 4 + 1][ss],
                                   sT[c4 * 4 + 2][ss], sT[c4 * 4 + 3][ss]);
            *(float4*)(g_R + (base + ss) * 64 + chunk * 32 + c4 * 4) = v;
        }
        __syncthreads();
    }
}

__global__ __launch_bounds__(256) void k_hinit(const float* __restrict__ W_embed,
                                               const int* __restrict__ atom_types) {
    int i = blockIdx.x * 256 + threadIdx.x;
    if (i >= Nn * 64) return;
    int n = i >> 6, c = i & 63;
    g_h[0][i] = W_embed[atom_types[n] * 64 + c];
}

__global__ __launch_bounds__(256) void k_lin(const float* __restrict__ Wup,
                                             const float* __restrict__ Wsc, int l) {
    int t = threadIdx.x;
    int node = blockIdx.x * 4 + (t >> 6);
    int lane = t & 63;
    const float* hin = g_h[l & 1];
    float hv = hin[node * 64 + lane];
    float a1 = 0.0f, a2 = 0.0f;
#pragma unroll
    for (int k = 0; k < 64; k++) {
        float hk = __shfl(hv, k, 64);
        a1 += hk * Wup[k * 64 + lane];
        a2 += hk * Wsc[k * 64 + lane];
    }
    g_h1[node * 64 + lane] = a1;
    g_hsc[node * 64 + lane] = a2;
}

// Merged gather+finish, wave per node: loop over 8-slot batches (coalesced
// record read, shfl unpack, 8 independent R + h1 loads), then epilogue.
// No g_P round-trip (saves ~112 MB/layer), no atomics, no csr indirection.
__global__ __launch_bounds__(256) void k_node0(const float* __restrict__ Wprod,
                                               const float* __restrict__ wro) {
    __shared__ float sP[4096];
    int t = threadIdx.x;
    for (int i = t; i < 4096; i += 256) sP[i] = Wprod[i];
    __syncthreads();
    int node = blockIdx.x * 4 + (t >> 6);
    int lane = t & 63;
    int boff = __builtin_amdgcn_readfirstlane(g_offs[node]);
    int nb = (__builtin_amdgcn_readfirstlane(g_deg[node]) + 7) >> 3;
    float A[9];
#pragma unroll
    for (int m = 0; m < 9; m++) A[m] = 0.0f;
    for (int b = 0; b < nb; b++) {
        size_t j0 = (size_t)boff + (size_t)b * 8;
        float4 rec = make_float4(0.f, 0.f, 0.f, 0.f);
        if (lane < 24) rec = *(const float4*)(g_shc + j0 * 12 + (size_t)lane * 4);
#pragma unroll
        for (int k = 0; k < 8; k++) {
            float s0 = __shfl(rec.x, 3 * k, 64), s1 = __shfl(rec.y, 3 * k, 64);
            float s2 = __shfl(rec.z, 3 * k, 64), s3 = __shfl(rec.w, 3 * k, 64);
            float s4 = __shfl(rec.x, 3 * k + 1, 64), s5 = __shfl(rec.y, 3 * k + 1, 64);
            float s6 = __shfl(rec.z, 3 * k + 1, 64), s7 = __shfl(rec.w, 3 * k + 1, 64);
            float s8 = __shfl(rec.x, 3 * k + 2, 64);
            int src = __float_as_int(__shfl(rec.y, 3 * k + 2, 64));
            float tv = g_R[(j0 + k) * 64 + lane] * g_h1[(size_t)src * 64 + lane];
            A[0] += s0 * tv; A[1] += s1 * tv; A[2] += s2 * tv;
            A[3] += s3 * tv; A[4] += s4 * tv; A[5] += s5 * tv;
            A[6] += s6 * tv; A[7] += s7 * tv; A[8] += s8 * tv;
        }
    }
    const float invn = 1.0f / 16.0f;  // AVG_NEI
    float q = A[0] * invn;
#pragma unroll
    for (int m = 0; m < 9; m++) {
        float a = A[m] * invn;
        q += a * a;
    }
    float hn = g_hsc[node * 64 + lane];
#pragma unroll
    for (int k = 0; k < 64; k++) {
        float qk = __shfl(q, k, 64);
        hn += qk * sP[k * 64 + lane];
    }
    g_h[1][node * 64 + lane] = hn;
    float v = hn * wro[lane];
#pragma unroll
    for (int off = 32; off > 0; off >>= 1) v += __shfl_down(v, off, 64);
    if (lane == 0) g_nodeE[0][node] = v;
}

// Layer-1: node_e = q.(Wprod@wro) + hsc.wro — no matvec, no h store.
__global__ __launch_bounds__(256) void k_node1(const float* __restrict__ wro) {
    int t = threadIdx.x;
    int node = blockIdx.x * 4 + (t >> 6);
    int lane = t & 63;
    int boff = __builtin_amdgcn_readfirstlane(g_offs[node]);
    int nb = (__builtin_amdgcn_readfirstlane(g_deg[node]) + 7) >> 3;
    float A[9];
#pragma unroll
    for (int m = 0; m < 9; m++) A[m] = 0.0f;
    for (int b = 0; b < nb; b++) {
        size_t j0 = (size_t)boff + (size_t)b * 8;
        float4 rec = make_float4(0.f, 0.f, 0.f, 0.f);
        if (lane < 24) rec = *(const float4*)(g_shc + j0 * 12 + (size_t)lane * 4);
#pragma unroll
        for (int k = 0; k < 8; k++) {
            float s0 = __shfl(rec.x, 3 * k, 64), s1 = __shfl(rec.y, 3 * k, 64);
            float s2 = __shfl(rec.z, 3 * k, 64), s3 = __shfl(rec.w, 3 * k, 64);
            float s4 = __shfl(rec.x, 3 * k + 1, 64), s5 = __shfl(rec.y, 3 * k + 1, 64);
            float s6 = __shfl(rec.z, 3 * k + 1, 64), s7 = __shfl(rec.w, 3 * k + 1, 64);
            float s8 = __shfl(rec.x, 3 * k + 2, 64);
            int src = __float_as_int(__shfl(rec.y, 3 * k + 2, 64));
            float tv = g_R[(j0 + k) * 64 + lane] * g_h1[(size_t)src * 64 + lane];
            A[0] += s0 * tv; A[1] += s1 * tv; A[2] += s2 * tv;
            A[3] += s3 * tv; A[4] += s4 * tv; A[5] += s5 * tv;
            A[6] += s6 * tv; A[7] += s7 * tv; A[8] += s8 * tv;
        }
    }
    const float invn = 1.0f / 16.0f;  // AVG_NEI
    float q = A[0] * invn;
#pragma unroll
    for (int m = 0; m < 9; m++) {
        float a = A[m] * invn;
        q += a * a;
    }
    float v = q * g_wpro[lane] + g_hsc[node * 64 + lane] * wro[lane];
#pragma unroll
    for (int off = 32; off > 0; off >>= 1) v += __shfl_down(v, off, 64);
    if (lane == 0) g_nodeE[1][node] = v;
}

// One wave per graph; batch is sorted -> binary-search the node range,
// coalesced reduce, single plain store. Zero atomics.
__global__ __launch_bounds__(64) void k_energy(const int* __restrict__ batch,
                                               float* __restrict__ out) {
    int g = blockIdx.x;
    int lane = threadIdx.x;
    int a = 0, b = Nn;
    while (a < b) { int m = (a + b) >> 1; if (batch[m] < g) a = m + 1; else b = m; }
    int st = a;
    b = Nn;
    while (a < b) { int m = (a + b) >> 1; if (batch[m] < g + 1) a = m + 1; else b = m; }
    int en = a;
    float s = 0.0f;
    for (int i = st + lane; i < en; i += 64) s += g_nodeE[0][i] + g_nodeE[1][i];
#pragma unroll
    for (int off = 32; off > 0; off >>= 1) s += __shfl_down(s, off, 64);
    if (lane == 0) out[g] = s;
}

extern "C" void kernel_launch(void* const* d_in, const int* in_sizes, int n_in,
                              void* d_out, int out_size, void* d_ws, size_t ws_size,
                              hipStream_t stream) {
    const float* pos     = (const float*)d_in[0];
    const float* W_embed = (const float*)d_in[1];
    const float* W_r1    = (const float*)d_in[2];
    const float* b_r1    = (const float*)d_in[3];
    const float* W_r2    = (const float*)d_in[4];
    const float* W_up    = (const float*)d_in[5];
    const float* W_sc    = (const float*)d_in[6];
    const float* W_prod  = (const float*)d_in[7];
    const float* w_ro    = (const float*)d_in[8];
    const int* atom_types = (const int*)d_in[9];
    const int* eidx       = (const int*)d_in[10];
    const int* batch      = (const int*)d_in[11];
    float* out = (float*)d_out;

    k_zero<<<CSRMAX / 256, 256, 0, stream>>>(out, out_size);
    k_deg<<<Ee / 256, 256, 0, stream>>>(eidx, W_r1, W_prod + 4096, w_ro + 64);
    k_scan<<<1, 1024, 0, stream>>>();
    k_fill<<<Ee / 256, 256, 0, stream>>>(eidx);
    k_edge<<<CSRMAX / 256, 512, 0, stream>>>(pos, b_r1, W_r2);
    k_hinit<<<(Nn * 64) / 256, 256, 0, stream>>>(W_embed, atom_types);

    k_lin<<<Nn / 4, 256, 0, stream>>>(W_up, W_sc, 0);
    k_node0<<<Nn / 4, 256, 0, stream>>>(W_prod, w_ro);

    k_lin<<<Nn / 4, 256, 0, stream>>>(W_up + 4096, W_sc + 4096, 1);
    k_node1<<<Nn / 4, 256, 0, stream>>>(w_ro + 64);

    k_energy<<<Gg, 64, 0, stream>>>(batch, out);
}

// Round 14
// 254.481 us; speedup vs baseline: 1.2246x; 1.2246x over previous
//
#include <hip/hip_runtime.h>
#include <math.h>

#define Nn 10000
#define Ee 160000
#define NBb 8
#define Gg 100
#define CSRMAX 230400            // >= Ee + 7*Nn, multiple of 256

// sh record per slot: [0..3]=sh0..3, [4..7]=sh4..7, [8]=sh8, [9]=src bits, [10,11]=0
__device__ __align__(16) float g_shc[(size_t)CSRMAX * 12];
__device__ __align__(16) float g_R[(size_t)CSRMAX * 64];    // [slot][64]
__device__ float g_h[2][Nn * 64];
__device__ float g_h1[Nn * 64];
__device__ float g_hsc[Nn * 64];
__device__ float g_nodeE[2][Nn];   // per-layer node energies (no atomics)
__device__ float g_wpro[64];       // W_prod[1] @ w_ro[1]
__device__ int   g_deg[Nn];
__device__ int   g_offs[Nn + 1];
__device__ int   g_cursor[Nn];
__device__ int2  g_er[CSRMAX];     // per-slot (sender, receiver); .x=-1 for pads
__device__ float g_W1T[64 * NBb];  // W_r1 transposed: [j][k]

__global__ __launch_bounds__(256) void k_zero(float* out, int out_size) {
    int i = blockIdx.x * 256 + threadIdx.x;
    if (i < CSRMAX) g_er[i].x = -1;
    if (i < out_size) out[i] = 0.0f;
    if (i < Nn) { g_deg[i] = 0; g_cursor[i] = 0; }
}

// degree count; block 0 also transposes W_r1 and computes W_prod[1]@w_ro[1]
__global__ __launch_bounds__(256) void k_deg(const int* __restrict__ eidx,
                                             const float* __restrict__ Wr1,
                                             const float* __restrict__ Wprod1,
                                             const float* __restrict__ wro1) {
    int e = blockIdx.x * 256 + threadIdx.x;
    if (e < Ee) atomicAdd(&g_deg[eidx[Ee + e]], 1);
    if (blockIdx.x == 0) {
        for (int i = threadIdx.x; i < 64 * NBb; i += 256) {
            int k = i >> 6, j = i & 63;  // Wr1[k][j]
            g_W1T[j * NBb + k] = Wr1[i];
        }
        if (threadIdx.x < 64) {
            int k = threadIdx.x;
            float s = 0.0f;
#pragma unroll
            for (int c = 0; c < 64; c++) s += Wprod1[k * 64 + c] * wro1[c];
            g_wpro[k] = s;
        }
    }
}

// prefix sum of degrees padded up to multiples of 8
__global__ __launch_bounds__(1024) void k_scan() {
    __shared__ int part[1024];
    int t = threadIdx.x;
    const int CH = (Nn + 1023) / 1024;  // 10
    int st = t * CH;
    int en = st + CH; if (en > Nn) en = Nn;
    int s = 0;
    for (int i = st; i < en; i++) s += (g_deg[i] + 7) & ~7;
    part[t] = s;
    __syncthreads();
    for (int d = 1; d < 1024; d <<= 1) {
        int v = (t >= d) ? part[t - d] : 0;
        __syncthreads();
        part[t] += v;
        __syncthreads();
    }
    int base = (t == 0) ? 0 : part[t - 1];
    for (int i = st; i < en; i++) { g_offs[i] = base; base += (g_deg[i] + 7) & ~7; }
    if (t == 1023) g_offs[Nn] = part[1023];
}

// fill slot records: pack (sender, receiver) so k_edge needs no eidx gather
__global__ __launch_bounds__(256) void k_fill(const int* __restrict__ eidx) {
    int e = blockIdx.x * 256 + threadIdx.x;
    if (e >= Ee) return;
    int snd = eidx[e];
    int r = eidx[Ee + e];
    int p = g_offs[r] + atomicAdd(&g_cursor[r], 1);
    g_er[p] = make_int2(snd, r);
}

// 512-thread blocks, 256 slots each: waves 0-3 compute channels 0-31,
// waves 4-7 channels 32-63. chalf is pinned into an SGPR via readfirstlane —
// COMPILER-VISIBLE uniformity is what keeps weights on the scalar path
// (r11: per-lane split, r13: true-but-unprovable uniformity both regressed).
__global__ __launch_bounds__(512) void k_edge(const float* __restrict__ pos,
                                              const float* __restrict__ br1,
                                              const float* __restrict__ Wr2) {
    __shared__ float sT[32][257];
    int t = threadIdx.x;
    int total = g_offs[Nn];
    if (blockIdx.x * 256 >= total) return;
    int slot = t & 255;
    int chalf = __builtin_amdgcn_readfirstlane(t >> 8);   // force SGPR
    int s = blockIdx.x * 256 + slot;
    int2 er = g_er[s];
    bool real = (er.x >= 0);
    int snd = real ? er.x : 0;
    int rcv = real ? er.y : 0;

    float vx = pos[3 * rcv + 0] - pos[3 * snd + 0];
    float vy = pos[3 * rcv + 1] - pos[3 * snd + 1];
    float vz = pos[3 * rcv + 2] - pos[3 * snd + 2];
    float r = sqrtf(vx * vx + vy * vy + vz * vz);
    float inv = __builtin_amdgcn_rcpf(fmaxf(r, 1e-9f));
    float x = vx * inv, y = vy * inv, z = vz * inv;
    const float s3 = 1.7320508f;
    if (chalf == 0) {
        float4* shp = (float4*)(g_shc + (size_t)s * 12);
        if (real) {
            shp[0] = make_float4(1.0f, x, y, z);
            shp[1] = make_float4(s3 * x * y, s3 * y * z, 0.5f * (3.0f * z * z - 1.0f), s3 * x * z);
            shp[2] = make_float4(0.5f * s3 * (x * x - y * y), __int_as_float(snd), 0.f, 0.f);
        } else {
            shp[0] = make_float4(0.f, 0.f, 0.f, 0.f);
            shp[1] = make_float4(0.f, 0.f, 0.f, 0.f);
            shp[2] = make_float4(0.f, 0.f, 0.f, 0.f);
        }
    }

    float xx = r * 0.2f;
    float env = 0.0f;
    if (xx < 1.0f) {
        float x2 = xx * xx;
        float x6 = x2 * x2 * x2;
        float x7 = x6 * xx;
        float x8 = x7 * xx;
        env = 1.0f - 28.0f * x6 + 48.0f * x7 - 21.0f * x8;
    }
    const float pref = 0.63245553f;  // sqrt(2/R_MAX)
    const float PI_F = 3.14159265358979f;
    float fac = pref * inv * env;
    float ef[NBb];
#pragma unroll
    for (int k = 0; k < NBb; k++)
        ef[k] = fac * __sinf((float)(k + 1) * PI_F * r * 0.2f);

    float acc[32];
#pragma unroll
    for (int c = 0; c < 32; c++) acc[c] = 0.0f;
    const float* __restrict__ w2base = Wr2 + chalf * 32;   // SGPR offset
    for (int j = 0; j < 64; j++) {
        float a = br1[j];
#pragma unroll
        for (int k = 0; k < NBb; k++) a += ef[k] * g_W1T[j * NBb + k];
        a = a * __builtin_amdgcn_rcpf(1.0f + __expf(-a));
        const float* __restrict__ w2 = w2base + j * 64;
#pragma unroll
        for (int c = 0; c < 32; c++) acc[c] += a * w2[c];
    }

    size_t base = (size_t)blockIdx.x * 256;
#pragma unroll
    for (int chunk = 0; chunk < 2; chunk++) {
        if (chalf == chunk) {
#pragma unroll
            for (int c = 0; c < 32; c++) sT[c][slot] = real ? acc[c] : 0.0f;
        }
        __syncthreads();
#pragma unroll
        for (int it = 0; it < 4; it++) {
            int idx = it * 512 + t;
            int ss = idx >> 3, c4 = idx & 7;
            float4 v = make_float4(sT[c4 * 4 + 0][ss], sT[c4 * 4 + 1][ss],
                                   sT[c4 * 4 + 2][ss], sT[c4 * 4 + 3][ss]);
            *(float4*)(g_R + (base + ss) * 64 + chunk * 32 + c4 * 4) = v;
        }
        __syncthreads();
    }
}

__global__ __launch_bounds__(256) void k_hinit(const float* __restrict__ W_embed,
                                               const int* __restrict__ atom_types) {
    int i = blockIdx.x * 256 + threadIdx.x;
    if (i >= Nn * 64) return;
    int n = i >> 6, c = i & 63;
    g_h[0][i] = W_embed[atom_types[n] * 64 + c];
}

__global__ __launch_bounds__(256) void k_lin(const float* __restrict__ Wup,
                                             const float* __restrict__ Wsc, int l) {
    int t = threadIdx.x;
    int node = blockIdx.x * 4 + (t >> 6);
    int lane = t & 63;
    const float* hin = g_h[l & 1];
    float hv = hin[node * 64 + lane];
    float a1 = 0.0f, a2 = 0.0f;
#pragma unroll
    for (int k = 0; k < 64; k++) {
        float hk = __shfl(hv, k, 64);
        a1 += hk * Wup[k * 64 + lane];
        a2 += hk * Wsc[k * 64 + lane];
    }
    g_h1[node * 64 + lane] = a1;
    g_hsc[node * 64 + lane] = a2;
}

// Merged gather+finish, wave per node: loop over 8-slot batches (coalesced
// record read, shfl unpack, 8 independent R + h1 loads), then epilogue.
__global__ __launch_bounds__(256) void k_node0(const float* __restrict__ Wprod,
                                               const float* __restrict__ wro) {
    __shared__ float sP[4096];
    int t = threadIdx.x;
    for (int i = t; i < 4096; i += 256) sP[i] = Wprod[i];
    __syncthreads();
    int node = blockIdx.x * 4 + (t >> 6);
    int lane = t & 63;
    int boff = __builtin_amdgcn_readfirstlane(g_offs[node]);
    int nb = (__builtin_amdgcn_readfirstlane(g_deg[node]) + 7) >> 3;
    float A[9];
#pragma unroll
    for (int m = 0; m < 9; m++) A[m] = 0.0f;
    for (int b = 0; b < nb; b++) {
        size_t j0 = (size_t)boff + (size_t)b * 8;
        float4 rec = make_float4(0.f, 0.f, 0.f, 0.f);
        if (lane < 24) rec = *(const float4*)(g_shc + j0 * 12 + (size_t)lane * 4);
#pragma unroll
        for (int k = 0; k < 8; k++) {
            float s0 = __shfl(rec.x, 3 * k, 64), s1 = __shfl(rec.y, 3 * k, 64);
            float s2 = __shfl(rec.z, 3 * k, 64), s3 = __shfl(rec.w, 3 * k, 64);
            float s4 = __shfl(rec.x, 3 * k + 1, 64), s5 = __shfl(rec.y, 3 * k + 1, 64);
            float s6 = __shfl(rec.z, 3 * k + 1, 64), s7 = __shfl(rec.w, 3 * k + 1, 64);
            float s8 = __shfl(rec.x, 3 * k + 2, 64);
            int src = __float_as_int(__shfl(rec.y, 3 * k + 2, 64));
            float tv = g_R[(j0 + k) * 64 + lane] * g_h1[(size_t)src * 64 + lane];
            A[0] += s0 * tv; A[1] += s1 * tv; A[2] += s2 * tv;
            A[3] += s3 * tv; A[4] += s4 * tv; A[5] += s5 * tv;
            A[6] += s6 * tv; A[7] += s7 * tv; A[8] += s8 * tv;
        }
    }
    const float invn = 1.0f / 16.0f;  // AVG_NEI
    float q = A[0] * invn;
#pragma unroll
    for (int m = 0; m < 9; m++) {
        float a = A[m] * invn;
        q += a * a;
    }
    float hn = g_hsc[node * 64 + lane];
#pragma unroll
    for (int k = 0; k < 64; k++) {
        float qk = __shfl(q, k, 64);
        hn += qk * sP[k * 64 + lane];
    }
    g_h[1][node * 64 + lane] = hn;
    float v = hn * wro[lane];
#pragma unroll
    for (int off = 32; off > 0; off >>= 1) v += __shfl_down(v, off, 64);
    if (lane == 0) g_nodeE[0][node] = v;
}

// Layer-1: node_e = q.(Wprod@wro) + hsc.wro — no matvec, no h store.
__global__ __launch_bounds__(256) void k_node1(const float* __restrict__ wro) {
    int t = threadIdx.x;
    int node = blockIdx.x * 4 + (t >> 6);
    int lane = t & 63;
    int boff = __builtin_amdgcn_readfirstlane(g_offs[node]);
    int nb = (__builtin_amdgcn_readfirstlane(g_deg[node]) + 7) >> 3;
    float A[9];
#pragma unroll
    for (int m = 0; m < 9; m++) A[m] = 0.0f;
    for (int b = 0; b < nb; b++) {
        size_t j0 = (size_t)boff + (size_t)b * 8;
        float4 rec = make_float4(0.f, 0.f, 0.f, 0.f);
        if (lane < 24) rec = *(const float4*)(g_shc + j0 * 12 + (size_t)lane * 4);
#pragma unroll
        for (int k = 0; k < 8; k++) {
            float s0 = __shfl(rec.x, 3 * k, 64), s1 = __shfl(rec.y, 3 * k, 64);
            float s2 = __shfl(rec.z, 3 * k, 64), s3 = __shfl(rec.w, 3 * k, 64);
            float s4 = __shfl(rec.x, 3 * k + 1, 64), s5 = __shfl(rec.y, 3 * k + 1, 64);
            float s6 = __shfl(rec.z, 3 * k + 1, 64), s7 = __shfl(rec.w, 3 * k + 1, 64);
            float s8 = __shfl(rec.x, 3 * k + 2, 64);
            int src = __float_as_int(__shfl(rec.y, 3 * k + 2, 64));
            float tv = g_R[(j0 + k) * 64 + lane] * g_h1[(size_t)src * 64 + lane];
            A[0] += s0 * tv; A[1] += s1 * tv; A[2] += s2 * tv;
            A[3] += s3 * tv; A[4] += s4 * tv; A[5] += s5 * tv;
            A[6] += s6 * tv; A[7] += s7 * tv; A[8] += s8 * tv;
        }
    }
    const float invn = 1.0f / 16.0f;  // AVG_NEI
    float q = A[0] * invn;
#pragma unroll
    for (int m = 0; m < 9; m++) {
        float a = A[m] * invn;
        q += a * a;
    }
    float v = q * g_wpro[lane] + g_hsc[node * 64 + lane] * wro[lane];
#pragma unroll
    for (int off = 32; off > 0; off >>= 1) v += __shfl_down(v, off, 64);
    if (lane == 0) g_nodeE[1][node] = v;
}

// One wave per graph; batch is sorted -> binary-search the node range,
// coalesced reduce, single plain store. Zero atomics.
__global__ __launch_bounds__(64) void k_energy(const int* __restrict__ batch,
                                               float* __restrict__ out) {
    int g = blockIdx.x;
    int lane = threadIdx.x;
    int a = 0, b = Nn;
    while (a < b) { int m = (a + b) >> 1; if (batch[m] < g) a = m + 1; else b = m; }
    int st = a;
    b = Nn;
    while (a < b) { int m = (a + b) >> 1; if (batch[m] < g + 1) a = m + 1; else b = m; }
    int en = a;
    float s = 0.0f;
    for (int i = st + lane; i < en; i += 64) s += g_nodeE[0][i] + g_nodeE[1][i];
#pragma unroll
    for (int off = 32; off > 0; off >>= 1) s += __shfl_down(s, off, 64);
    if (lane == 0) out[g] = s;
}

extern "C" void kernel_launch(void* const* d_in, const int* in_sizes, int n_in,
                              void* d_out, int out_size, void* d_ws, size_t ws_size,
                              hipStream_t stream) {
    const float* pos     = (const float*)d_in[0];
    const float* W_embed = (const float*)d_in[1];
    const float* W_r1    = (const float*)d_in[2];
    const float* b_r1    = (const float*)d_in[3];
    const float* W_r2    = (const float*)d_in[4];
    const float* W_up    = (const float*)d_in[5];
    const float* W_sc    = (const float*)d_in[6];
    const float* W_prod  = (const float*)d_in[7];
    const float* w_ro    = (const float*)d_in[8];
    const int* atom_types = (const int*)d_in[9];
    const int* eidx       = (const int*)d_in[10];
    const int* batch      = (const int*)d_in[11];
    float* out = (float*)d_out;

    k_zero<<<CSRMAX / 256, 256, 0, stream>>>(out, out_size);
    k_deg<<<Ee / 256, 256, 0, stream>>>(eidx, W_r1, W_prod + 4096, w_ro + 64);
    k_scan<<<1, 1024, 0, stream>>>();
    k_fill<<<Ee / 256, 256, 0, stream>>>(eidx);
    k_edge<<<CSRMAX / 256, 512, 0, stream>>>(pos, b_r1, W_r2);
    k_hinit<<<(Nn * 64) / 256, 256, 0, stream>>>(W_embed, atom_types);

    k_lin<<<Nn / 4, 256, 0, stream>>>(W_up, W_sc, 0);
    k_node0<<<Nn / 4, 256, 0, stream>>>(W_prod, w_ro);

    k_lin<<<Nn / 4, 256, 0, stream>>>(W_up + 4096, W_sc + 4096, 1);
    k_node1<<<Nn / 4, 256, 0, stream>>>(w_ro + 64);

    k_energy<<<Gg, 64, 0, stream>>>(batch, out);
}

// Round 15
// 235.962 us; speedup vs baseline: 1.3207x; 1.0785x over previous
//
#include <hip/hip_runtime.h>
#include <math.h>

#define Nn 10000
#define Ee 160000
#define NBb 8
#define Gg 100
#define NT 5
#define CSRMAX 230400            // >= Ee + 7*Nn, multiple of 256

// sh record per slot: [0..3]=sh0..3, [4..7]=sh4..7, [8]=sh8, [9]=src bits, [10,11]=0
__device__ __align__(16) float g_shc[(size_t)CSRMAX * 12];
__device__ __align__(16) float g_R[(size_t)CSRMAX * 64];    // [slot][64]
__device__ float g_h1a[Nn * 64];   // layer-0 h@Wup0 (= E1[type])
__device__ float g_h1b[Nn * 64];   // layer-1 h'@Wup1
__device__ float g_hscb[Nn * 64];  // layer-1 h'@Wsc1
__device__ float g_nodeE[2][Nn];   // per-layer node energies (no atomics)
__device__ int   g_deg[Nn];
__device__ int   g_offs[Nn + 1];
__device__ int   g_cursor[Nn];
__device__ int2  g_er[CSRMAX];     // per-slot (sender, receiver); .x=-1 for pads
// precomputed algebra (k_prep)
__device__ float g_W1T[64 * NBb];  // W_r1 transposed: [j][k]
__device__ float g_E1[NT * 64];    // Wembed@Wup0
__device__ float g_Esc[NT * 64];   // Wembed@Wsc0 (scratch for T1/T2/t0)
__device__ float g_T1[NT * 64];    // Esc@Wup1
__device__ float g_T2[NT * 64];    // Esc@Wsc1
__device__ float g_M1[64 * 64];    // Wp0@Wup1
__device__ float g_M2[64 * 64];    // Wp0@Wsc1
__device__ float g_wp0ro[64];      // Wp0@wro0
__device__ float g_wpro[64];       // Wp1@wro1
__device__ float g_t0[NT];         // Esc@wro0

__global__ __launch_bounds__(256) void k_zero(float* out, int out_size) {
    int i = blockIdx.x * 256 + threadIdx.x;
    if (i < CSRMAX) g_er[i].x = -1;
    if (i < out_size) out[i] = 0.0f;
    if (i < Nn) { g_deg[i] = 0; g_cursor[i] = 0; }
}

// Precompute all fused linear-algebra tables. Block 0: small stuff (with an
// internal sync for the Esc -> T1/T2/t0 dependency). Blocks 1..16: M1/M2.
__global__ __launch_bounds__(256) void k_prep(const float* __restrict__ Wr1,
                                              const float* __restrict__ Wembed,
                                              const float* __restrict__ Wup,
                                              const float* __restrict__ Wsc,
                                              const float* __restrict__ Wprod,
                                              const float* __restrict__ wro) {
    int t = threadIdx.x;
    int b = blockIdx.x;
    if (b == 0) {
        for (int i = t; i < 64 * NBb; i += 256) {
            int k = i >> 6, j = i & 63;  // Wr1[k][j]
            g_W1T[j * NBb + k] = Wr1[i];
        }
        for (int i = t; i < NT * 64; i += 256) {
            int g = i >> 6, c = i & 63;
            float s1 = 0.f, s2 = 0.f;
            for (int j = 0; j < 64; j++) {
                float w = Wembed[g * 64 + j];
                s1 += w * Wup[j * 64 + c];
                s2 += w * Wsc[j * 64 + c];
            }
            g_E1[i] = s1; g_Esc[i] = s2;
        }
        if (t < 64) {
            float s1 = 0.f, s2 = 0.f;
            for (int c = 0; c < 64; c++) {
                s1 += Wprod[t * 64 + c] * wro[c];
                s2 += Wprod[4096 + t * 64 + c] * wro[64 + c];
            }
            g_wp0ro[t] = s1; g_wpro[t] = s2;
        }
        __syncthreads();
        for (int i = t; i < NT * 64; i += 256) {
            int g = i >> 6, c = i & 63;
            float s1 = 0.f, s2 = 0.f;
            for (int j = 0; j < 64; j++) {
                float w = g_Esc[g * 64 + j];
                s1 += w * Wup[4096 + j * 64 + c];
                s2 += w * Wsc[4096 + j * 64 + c];
            }
            g_T1[i] = s1; g_T2[i] = s2;
        }
        if (t < NT) {
            float s = 0.f;
            for (int j = 0; j < 64; j++) s += g_Esc[t * 64 + j] * wro[j];
            g_t0[t] = s;
        }
    } else {
        int idx = (b - 1) * 256 + t;          // 0..4095
        int k = idx >> 6, c = idx & 63;
        float s1 = 0.f, s2 = 0.f;
        for (int j = 0; j < 64; j++) {
            float w = Wprod[k * 64 + j];       // wave-uniform -> scalar
            s1 += w * Wup[4096 + j * 64 + c];
            s2 += w * Wsc[4096 + j * 64 + c];
        }
        g_M1[idx] = s1; g_M2[idx] = s2;
    }
}

__global__ __launch_bounds__(256) void k_deg(const int* __restrict__ eidx) {
    int e = blockIdx.x * 256 + threadIdx.x;
    if (e < Ee) atomicAdd(&g_deg[eidx[Ee + e]], 1);
}

// prefix sum of degrees padded up to multiples of 8
__global__ __launch_bounds__(1024) void k_scan() {
    __shared__ int part[1024];
    int t = threadIdx.x;
    const int CH = (Nn + 1023) / 1024;  // 10
    int st = t * CH;
    int en = st + CH; if (en > Nn) en = Nn;
    int s = 0;
    for (int i = st; i < en; i++) s += (g_deg[i] + 7) & ~7;
    part[t] = s;
    __syncthreads();
    for (int d = 1; d < 1024; d <<= 1) {
        int v = (t >= d) ? part[t - d] : 0;
        __syncthreads();
        part[t] += v;
        __syncthreads();
    }
    int base = (t == 0) ? 0 : part[t - 1];
    for (int i = st; i < en; i++) { g_offs[i] = base; base += (g_deg[i] + 7) & ~7; }
    if (t == 1023) g_offs[Nn] = part[1023];
}

__global__ __launch_bounds__(256) void k_fill(const int* __restrict__ eidx) {
    int e = blockIdx.x * 256 + threadIdx.x;
    if (e >= Ee) return;
    int snd = eidx[e];
    int r = eidx[Ee + e];
    int p = g_offs[r] + atomicAdd(&g_cursor[r], 1);
    g_er[p] = make_int2(snd, r);
}

// 512-thread blocks, 256 slots each: waves 0-3 -> channels 0-31, waves 4-7 ->
// 32-63. chalf pinned to SGPR via readfirstlane: COMPILER-VISIBLE uniformity
// keeps weights on the scalar path (r11/r13 regressions taught this).
__global__ __launch_bounds__(512) void k_edge(const float* __restrict__ pos,
                                              const float* __restrict__ br1,
                                              const float* __restrict__ Wr2) {
    __shared__ float sT[32][257];
    int t = threadIdx.x;
    int total = g_offs[Nn];
    if (blockIdx.x * 256 >= total) return;
    int slot = t & 255;
    int chalf = __builtin_amdgcn_readfirstlane(t >> 8);   // force SGPR
    int s = blockIdx.x * 256 + slot;
    int2 er = g_er[s];
    bool real = (er.x >= 0);
    int snd = real ? er.x : 0;
    int rcv = real ? er.y : 0;

    float vx = pos[3 * rcv + 0] - pos[3 * snd + 0];
    float vy = pos[3 * rcv + 1] - pos[3 * snd + 1];
    float vz = pos[3 * rcv + 2] - pos[3 * snd + 2];
    float r = sqrtf(vx * vx + vy * vy + vz * vz);
    float inv = __builtin_amdgcn_rcpf(fmaxf(r, 1e-9f));
    float x = vx * inv, y = vy * inv, z = vz * inv;
    const float s3 = 1.7320508f;
    if (chalf == 0) {
        float4* shp = (float4*)(g_shc + (size_t)s * 12);
        if (real) {
            shp[0] = make_float4(1.0f, x, y, z);
            shp[1] = make_float4(s3 * x * y, s3 * y * z, 0.5f * (3.0f * z * z - 1.0f), s3 * x * z);
            shp[2] = make_float4(0.5f * s3 * (x * x - y * y), __int_as_float(snd), 0.f, 0.f);
        } else {
            shp[0] = make_float4(0.f, 0.f, 0.f, 0.f);
            shp[1] = make_float4(0.f, 0.f, 0.f, 0.f);
            shp[2] = make_float4(0.f, 0.f, 0.f, 0.f);
        }
    }

    float xx = r * 0.2f;
    float env = 0.0f;
    if (xx < 1.0f) {
        float x2 = xx * xx;
        float x6 = x2 * x2 * x2;
        float x7 = x6 * xx;
        float x8 = x7 * xx;
        env = 1.0f - 28.0f * x6 + 48.0f * x7 - 21.0f * x8;
    }
    const float pref = 0.63245553f;  // sqrt(2/R_MAX)
    const float PI_F = 3.14159265358979f;
    float fac = pref * inv * env;
    float ef[NBb];
#pragma unroll
    for (int k = 0; k < NBb; k++)
        ef[k] = fac * __sinf((float)(k + 1) * PI_F * r * 0.2f);

    float acc[32];
#pragma unroll
    for (int c = 0; c < 32; c++) acc[c] = 0.0f;
    const float* __restrict__ w2base = Wr2 + chalf * 32;   // SGPR offset
    for (int j = 0; j < 64; j++) {
        float a = br1[j];
#pragma unroll
        for (int k = 0; k < NBb; k++) a += ef[k] * g_W1T[j * NBb + k];
        a = a * __builtin_amdgcn_rcpf(1.0f + __expf(-a));
        const float* __restrict__ w2 = w2base + j * 64;
#pragma unroll
        for (int c = 0; c < 32; c++) acc[c] += a * w2[c];
    }

    size_t base = (size_t)blockIdx.x * 256;
#pragma unroll
    for (int chunk = 0; chunk < 2; chunk++) {
        if (chalf == chunk) {
#pragma unroll
            for (int c = 0; c < 32; c++) sT[c][slot] = real ? acc[c] : 0.0f;
        }
        __syncthreads();
#pragma unroll
        for (int it = 0; it < 4; it++) {
            int idx = it * 512 + t;
            int ss = idx >> 3, c4 = idx & 7;
            float4 v = make_float4(sT[c4 * 4 + 0][ss], sT[c4 * 4 + 1][ss],
                                   sT[c4 * 4 + 2][ss], sT[c4 * 4 + 3][ss]);
            *(float4*)(g_R + (base + ss) * 64 + chunk * 32 + c4 * 4) = v;
        }
        __syncthreads();
    }
}

// h1 (layer 0) is a pure table lookup: one-hot embed folded through Wup0.
__global__ __launch_bounds__(256) void k_hinit(const int* __restrict__ atom_types) {
    int i = blockIdx.x * 256 + threadIdx.x;
    if (i >= Nn * 64) return;
    int n = i >> 6, c = i & 63;
    g_h1a[i] = g_E1[atom_types[n] * 64 + c];
}

// Layer-0 node kernel: gather A, q, then DIRECTLY produce layer-1 inputs
// h1b = q@M1 + T1[type], hscb = q@M2 + T2[type], and
// nodeE0 = q.wp0ro + t0[type]  (h never materialized; k_lin eliminated).
__global__ __launch_bounds__(256) void k_node0(const int* __restrict__ atom_types) {
    int t = threadIdx.x;
    int node = blockIdx.x * 4 + (t >> 6);
    int lane = t & 63;
    int boff = __builtin_amdgcn_readfirstlane(g_offs[node]);
    int nb = (__builtin_amdgcn_readfirstlane(g_deg[node]) + 7) >> 3;
    float A[9];
#pragma unroll
    for (int m = 0; m < 9; m++) A[m] = 0.0f;
    for (int b = 0; b < nb; b++) {
        size_t j0 = (size_t)boff + (size_t)b * 8;
        float4 rec = make_float4(0.f, 0.f, 0.f, 0.f);
        if (lane < 24) rec = *(const float4*)(g_shc + j0 * 12 + (size_t)lane * 4);
#pragma unroll
        for (int k = 0; k < 8; k++) {
            float s0 = __shfl(rec.x, 3 * k, 64), s1 = __shfl(rec.y, 3 * k, 64);
            float s2 = __shfl(rec.z, 3 * k, 64), s3 = __shfl(rec.w, 3 * k, 64);
            float s4 = __shfl(rec.x, 3 * k + 1, 64), s5 = __shfl(rec.y, 3 * k + 1, 64);
            float s6 = __shfl(rec.z, 3 * k + 1, 64), s7 = __shfl(rec.w, 3 * k + 1, 64);
            float s8 = __shfl(rec.x, 3 * k + 2, 64);
            int src = __float_as_int(__shfl(rec.y, 3 * k + 2, 64));
            float tv = g_R[(j0 + k) * 64 + lane] * g_h1a[(size_t)src * 64 + lane];
            A[0] += s0 * tv; A[1] += s1 * tv; A[2] += s2 * tv;
            A[3] += s3 * tv; A[4] += s4 * tv; A[5] += s5 * tv;
            A[6] += s6 * tv; A[7] += s7 * tv; A[8] += s8 * tv;
        }
    }
    const float invn = 1.0f / 16.0f;  // AVG_NEI
    float q = A[0] * invn;
#pragma unroll
    for (int m = 0; m < 9; m++) {
        float a = A[m] * invn;
        q += a * a;
    }
    int type = __builtin_amdgcn_readfirstlane(atom_types[node]);
    float h1n = g_T1[type * 64 + lane];
    float hscn = g_T2[type * 64 + lane];
#pragma unroll
    for (int k = 0; k < 64; k++) {
        float qk = __shfl(q, k, 64);
        h1n += qk * g_M1[k * 64 + lane];
        hscn += qk * g_M2[k * 64 + lane];
    }
    g_h1b[node * 64 + lane] = h1n;
    g_hscb[node * 64 + lane] = hscn;
    float v = q * g_wp0ro[lane];
#pragma unroll
    for (int off = 32; off > 0; off >>= 1) v += __shfl_down(v, off, 64);
    if (lane == 0) g_nodeE[0][node] = v + g_t0[type];
}

// Layer-1: node_e = q.(Wp1@wro1) + hscb.wro1 — no matvec, no h store.
__global__ __launch_bounds__(256) void k_node1(const float* __restrict__ wro) {
    int t = threadIdx.x;
    int node = blockIdx.x * 4 + (t >> 6);
    int lane = t & 63;
    int boff = __builtin_amdgcn_readfirstlane(g_offs[node]);
    int nb = (__builtin_amdgcn_readfirstlane(g_deg[node]) + 7) >> 3;
    float A[9];
#pragma unroll
    for (int m = 0; m < 9; m++) A[m] = 0.0f;
    for (int b = 0; b < nb; b++) {
        size_t j0 = (size_t)boff + (size_t)b * 8;
        float4 rec = make_float4(0.f, 0.f, 0.f, 0.f);
        if (lane < 24) rec = *(const float4*)(g_shc + j0 * 12 + (size_t)lane * 4);
#pragma unroll
        for (int k = 0; k < 8; k++) {
            float s0 = __shfl(rec.x, 3 * k, 64), s1 = __shfl(rec.y, 3 * k, 64);
            float s2 = __shfl(rec.z, 3 * k, 64), s3 = __shfl(rec.w, 3 * k, 64);
            float s4 = __shfl(rec.x, 3 * k + 1, 64), s5 = __shfl(rec.y, 3 * k + 1, 64);
            float s6 = __shfl(rec.z, 3 * k + 1, 64), s7 = __shfl(rec.w, 3 * k + 1, 64);
            float s8 = __shfl(rec.x, 3 * k + 2, 64);
            int src = __float_as_int(__shfl(rec.y, 3 * k + 2, 64));
            float tv = g_R[(j0 + k) * 64 + lane] * g_h1b[(size_t)src * 64 + lane];
            A[0] += s0 * tv; A[1] += s1 * tv; A[2] += s2 * tv;
            A[3] += s3 * tv; A[4] += s4 * tv; A[5] += s5 * tv;
            A[6] += s6 * tv; A[7] += s7 * tv; A[8] += s8 * tv;
        }
    }
    const float invn = 1.0f / 16.0f;  // AVG_NEI
    float q = A[0] * invn;
#pragma unroll
    for (int m = 0; m < 9; m++) {
        float a = A[m] * invn;
        q += a * a;
    }
    float v = q * g_wpro[lane] + g_hscb[node * 64 + lane] * wro[lane];
#pragma unroll
    for (int off = 32; off > 0; off >>= 1) v += __shfl_down(v, off, 64);
    if (lane == 0) g_nodeE[1][node] = v;
}

// One wave per graph; batch is sorted -> binary-search the node range,
// coalesced reduce, single plain store. Zero atomics.
__global__ __launch_bounds__(64) void k_energy(const int* __restrict__ batch,
                                               float* __restrict__ out) {
    int g = blockIdx.x;
    int lane = threadIdx.x;
    int a = 0, b = Nn;
    while (a < b) { int m = (a + b) >> 1; if (batch[m] < g) a = m + 1; else b = m; }
    int st = a;
    b = Nn;
    while (a < b) { int m = (a + b) >> 1; if (batch[m] < g + 1) a = m + 1; else b = m; }
    int en = a;
    float s = 0.0f;
    for (int i = st + lane; i < en; i += 64) s += g_nodeE[0][i] + g_nodeE[1][i];
#pragma unroll
    for (int off = 32; off > 0; off >>= 1) s += __shfl_down(s, off, 64);
    if (lane == 0) out[g] = s;
}

extern "C" void kernel_launch(void* const* d_in, const int* in_sizes, int n_in,
                              void* d_out, int out_size, void* d_ws, size_t ws_size,
                              hipStream_t stream) {
    const float* pos     = (const float*)d_in[0];
    const float* W_embed = (const float*)d_in[1];
    const float* W_r1    = (const float*)d_in[2];
    const float* b_r1    = (const float*)d_in[3];
    const float* W_r2    = (const float*)d_in[4];
    const float* W_up    = (const float*)d_in[5];
    const float* W_sc    = (const float*)d_in[6];
    const float* W_prod  = (const float*)d_in[7];
    const float* w_ro    = (const float*)d_in[8];
    const int* atom_types = (const int*)d_in[9];
    const int* eidx       = (const int*)d_in[10];
    const int* batch      = (const int*)d_in[11];
    float* out = (float*)d_out;

    k_zero<<<CSRMAX / 256, 256, 0, stream>>>(out, out_size);
    k_prep<<<17, 256, 0, stream>>>(W_r1, W_embed, W_up, W_sc, W_prod, w_ro);
    k_deg<<<Ee / 256, 256, 0, stream>>>(eidx);
    k_scan<<<1, 1024, 0, stream>>>();
    k_fill<<<Ee / 256, 256, 0, stream>>>(eidx);
    k_edge<<<CSRMAX / 256, 512, 0, stream>>>(pos, b_r1, W_r2);
    k_hinit<<<(Nn * 64) / 256, 256, 0, stream>>>(atom_types);

    k_node0<<<Nn / 4, 256, 0, stream>>>(atom_types);
    k_node1<<<Nn / 4, 256, 0, stream>>>(w_ro + 64);

    k_energy<<<Gg, 64, 0, stream>>>(batch, out);
}

// Round 16
// 226.358 us; speedup vs baseline: 1.3768x; 1.0424x over previous
//
#include <hip/hip_runtime.h>
#include <math.h>

#define Nn 10000
#define Ee 160000
#define NBb 8
#define Gg 100
#define NT 5
#define CSRMAX 230400            // >= Ee + 7*Nn, multiple of 256
#define EDGEBLK (CSRMAX / 256)   // 900

// sh record per slot: [0..3]=sh0..3, [4..7]=sh4..7, [8]=sh8, [9]=src bits, [10,11]=0
__device__ __align__(16) float g_shc[(size_t)CSRMAX * 12];
__device__ __align__(16) float g_R[(size_t)CSRMAX * 64];    // [slot][64]
__device__ float g_h1a[Nn * 64];   // layer-0 h@Wup0 (= E1[type])
__device__ float g_h1b[Nn * 64];   // layer-1 h'@Wup1
__device__ float g_hscb[Nn * 64];  // layer-1 h'@Wsc1
__device__ float g_nodeE[2][Nn];   // per-layer node energies (no atomics)
__device__ int   g_deg[Nn];
__device__ int   g_offs[Nn + 1];
__device__ int   g_cursor[Nn];
__device__ int2  g_er[CSRMAX];     // per-slot (sender, receiver); .x=-1 for pads
// precomputed algebra (k_init)
__device__ float g_W1T[64 * NBb];  // W_r1 transposed: [j][k]
__device__ float g_E1[NT * 64];    // Wembed@Wup0
__device__ float g_Esc[NT * 64];   // Wembed@Wsc0 (scratch)
__device__ float g_T1[NT * 64];    // Esc@Wup1
__device__ float g_T2[NT * 64];    // Esc@Wsc1
__device__ float g_M12[64 * 128];  // [k][0:64]=Wp0@Wup1 row, [k][64:128]=Wp0@Wsc1 row
__device__ float g_wp0ro[64];      // Wp0@wro0
__device__ float g_wpro[64];       // Wp1@wro1
__device__ float g_t0[NT];         // Esc@wro0

// Fused: blocks 0-16 precompute algebra tables; blocks 17.. zero/init state.
__global__ __launch_bounds__(256) void k_init(const float* __restrict__ Wr1,
                                              const float* __restrict__ Wembed,
                                              const float* __restrict__ Wup,
                                              const float* __restrict__ Wsc,
                                              const float* __restrict__ Wprod,
                                              const float* __restrict__ wro,
                                              float* __restrict__ out, int out_size) {
    int t = threadIdx.x;
    int b = blockIdx.x;
    if (b >= 17) {
        int i = (b - 17) * 256 + t;
        if (i < CSRMAX) g_er[i].x = -1;
        if (i < out_size) out[i] = 0.0f;
        if (i < Nn) { g_deg[i] = 0; g_cursor[i] = 0; }
        return;
    }
    if (b == 0) {
        for (int i = t; i < 64 * NBb; i += 256) {
            int k = i >> 6, j = i & 63;  // Wr1[k][j]
            g_W1T[j * NBb + k] = Wr1[i];
        }
        for (int i = t; i < NT * 64; i += 256) {
            int g = i >> 6, c = i & 63;
            float s1 = 0.f, s2 = 0.f;
            for (int j = 0; j < 64; j++) {
                float w = Wembed[g * 64 + j];
                s1 += w * Wup[j * 64 + c];
                s2 += w * Wsc[j * 64 + c];
            }
            g_E1[i] = s1; g_Esc[i] = s2;
        }
        if (t < 64) {
            float s1 = 0.f, s2 = 0.f;
            for (int c = 0; c < 64; c++) {
                s1 += Wprod[t * 64 + c] * wro[c];
                s2 += Wprod[4096 + t * 64 + c] * wro[64 + c];
            }
            g_wp0ro[t] = s1; g_wpro[t] = s2;
        }
        __syncthreads();
        for (int i = t; i < NT * 64; i += 256) {
            int g = i >> 6, c = i & 63;
            float s1 = 0.f, s2 = 0.f;
            for (int j = 0; j < 64; j++) {
                float w = g_Esc[g * 64 + j];
                s1 += w * Wup[4096 + j * 64 + c];
                s2 += w * Wsc[4096 + j * 64 + c];
            }
            g_T1[i] = s1; g_T2[i] = s2;
        }
        if (t < NT) {
            float s = 0.f;
            for (int j = 0; j < 64; j++) s += g_Esc[t * 64 + j] * wro[j];
            g_t0[t] = s;
        }
    } else {
        int idx = (b - 1) * 256 + t;          // 0..4095
        int k = idx >> 6, c = idx & 63;
        float s1 = 0.f, s2 = 0.f;
        for (int j = 0; j < 64; j++) {
            float w = Wprod[k * 64 + j];       // wave-uniform -> scalar
            s1 += w * Wup[4096 + j * 64 + c];
            s2 += w * Wsc[4096 + j * 64 + c];
        }
        g_M12[k * 128 + c] = s1;
        g_M12[k * 128 + 64 + c] = s2;
    }
}

__global__ __launch_bounds__(256) void k_deg(const int* __restrict__ eidx) {
    int e = blockIdx.x * 256 + threadIdx.x;
    if (e < Ee) atomicAdd(&g_deg[eidx[Ee + e]], 1);
}

// prefix sum of degrees padded up to multiples of 8
__global__ __launch_bounds__(1024) void k_scan() {
    __shared__ int part[1024];
    int t = threadIdx.x;
    const int CH = (Nn + 1023) / 1024;  // 10
    int st = t * CH;
    int en = st + CH; if (en > Nn) en = Nn;
    int s = 0;
    for (int i = st; i < en; i++) s += (g_deg[i] + 7) & ~7;
    part[t] = s;
    __syncthreads();
    for (int d = 1; d < 1024; d <<= 1) {
        int v = (t >= d) ? part[t - d] : 0;
        __syncthreads();
        part[t] += v;
        __syncthreads();
    }
    int base = (t == 0) ? 0 : part[t - 1];
    for (int i = st; i < en; i++) { g_offs[i] = base; base += (g_deg[i] + 7) & ~7; }
    if (t == 1023) g_offs[Nn] = part[1023];
}

__global__ __launch_bounds__(256) void k_fill(const int* __restrict__ eidx) {
    int e = blockIdx.x * 256 + threadIdx.x;
    if (e >= Ee) return;
    int snd = eidx[e];
    int r = eidx[Ee + e];
    int p = g_offs[r] + atomicAdd(&g_cursor[r], 1);
    g_er[p] = make_int2(snd, r);
}

// Blocks < EDGEBLK: edge MLP (512 thr = 2 wave-groups; chalf pinned to SGPR —
// compiler-visible uniformity keeps weights on the scalar path; r11/r13 taught
// this). Blocks >= EDGEBLK: h1a init (fused former k_hinit).
__global__ __launch_bounds__(512) void k_edge(const float* __restrict__ pos,
                                              const float* __restrict__ br1,
                                              const float* __restrict__ Wr2,
                                              const int* __restrict__ atom_types) {
    int t = threadIdx.x;
    if (blockIdx.x >= EDGEBLK) {
        int i = (blockIdx.x - EDGEBLK) * 512 + t;
        if (i < Nn * 64) {
            int n = i >> 6, c = i & 63;
            g_h1a[i] = g_E1[atom_types[n] * 64 + c];
        }
        return;
    }
    __shared__ float sT[32][257];
    int total = g_offs[Nn];
    if (blockIdx.x * 256 >= total) return;
    int slot = t & 255;
    int chalf = __builtin_amdgcn_readfirstlane(t >> 8);   // force SGPR
    int s = blockIdx.x * 256 + slot;
    int2 er = g_er[s];
    bool real = (er.x >= 0);
    int snd = real ? er.x : 0;
    int rcv = real ? er.y : 0;

    float vx = pos[3 * rcv + 0] - pos[3 * snd + 0];
    float vy = pos[3 * rcv + 1] - pos[3 * snd + 1];
    float vz = pos[3 * rcv + 2] - pos[3 * snd + 2];
    float r = sqrtf(vx * vx + vy * vy + vz * vz);
    float inv = __builtin_amdgcn_rcpf(fmaxf(r, 1e-9f));
    float x = vx * inv, y = vy * inv, z = vz * inv;
    const float s3 = 1.7320508f;
    if (chalf == 0) {
        float4* shp = (float4*)(g_shc + (size_t)s * 12);
        if (real) {
            shp[0] = make_float4(1.0f, x, y, z);
            shp[1] = make_float4(s3 * x * y, s3 * y * z, 0.5f * (3.0f * z * z - 1.0f), s3 * x * z);
            shp[2] = make_float4(0.5f * s3 * (x * x - y * y), __int_as_float(snd), 0.f, 0.f);
        } else {
            shp[0] = make_float4(0.f, 0.f, 0.f, 0.f);
            shp[1] = make_float4(0.f, 0.f, 0.f, 0.f);
            shp[2] = make_float4(0.f, 0.f, 0.f, 0.f);
        }
    }

    float xx = r * 0.2f;
    float env = 0.0f;
    if (xx < 1.0f) {
        float x2 = xx * xx;
        float x6 = x2 * x2 * x2;
        float x7 = x6 * xx;
        float x8 = x7 * xx;
        env = 1.0f - 28.0f * x6 + 48.0f * x7 - 21.0f * x8;
    }
    const float pref = 0.63245553f;  // sqrt(2/R_MAX)
    const float PI_F = 3.14159265358979f;
    float fac = pref * inv * env;
    float ef[NBb];
#pragma unroll
    for (int k = 0; k < NBb; k++)
        ef[k] = fac * __sinf((float)(k + 1) * PI_F * r * 0.2f);

    float acc[32];
#pragma unroll
    for (int c = 0; c < 32; c++) acc[c] = 0.0f;
    const float* __restrict__ w2base = Wr2 + chalf * 32;   // SGPR offset
    for (int j = 0; j < 64; j++) {
        float a = br1[j];
#pragma unroll
        for (int k = 0; k < NBb; k++) a += ef[k] * g_W1T[j * NBb + k];
        a = a * __builtin_amdgcn_rcpf(1.0f + __expf(-a));
        const float* __restrict__ w2 = w2base + j * 64;
#pragma unroll
        for (int c = 0; c < 32; c++) acc[c] += a * w2[c];
    }

    size_t base = (size_t)blockIdx.x * 256;
#pragma unroll
    for (int chunk = 0; chunk < 2; chunk++) {
        if (chalf == chunk) {
#pragma unroll
            for (int c = 0; c < 32; c++) sT[c][slot] = real ? acc[c] : 0.0f;
        }
        __syncthreads();
#pragma unroll
        for (int it = 0; it < 4; it++) {
            int idx = it * 512 + t;
            int ss = idx >> 3, c4 = idx & 7;
            float4 v = make_float4(sT[c4 * 4 + 0][ss], sT[c4 * 4 + 1][ss],
                                   sT[c4 * 4 + 2][ss], sT[c4 * 4 + 3][ss]);
            *(float4*)(g_R + (base + ss) * 64 + chunk * 32 + c4 * 4) = v;
        }
        __syncthreads();
    }
}

#define PROCESS_BATCH(rec, j0)                                                   \
    {                                                                            \
        _Pragma("unroll")                                                        \
        for (int k = 0; k < 8; k++) {                                            \
            float s0 = __shfl(rec.x, 3 * k, 64), s1 = __shfl(rec.y, 3 * k, 64);  \
            float s2 = __shfl(rec.z, 3 * k, 64), s3 = __shfl(rec.w, 3 * k, 64);  \
            float s4 = __shfl(rec.x, 3 * k + 1, 64), s5 = __shfl(rec.y, 3 * k + 1, 64); \
            float s6 = __shfl(rec.z, 3 * k + 1, 64), s7 = __shfl(rec.w, 3 * k + 1, 64); \
            float s8 = __shfl(rec.x, 3 * k + 2, 64);                             \
            int src = __float_as_int(__shfl(rec.y, 3 * k + 2, 64));              \
            float tv = g_R[((j0) + k) * 64 + lane] * hsrc[(size_t)src * 64 + lane]; \
            A[0] += s0 * tv; A[1] += s1 * tv; A[2] += s2 * tv;                   \
            A[3] += s3 * tv; A[4] += s4 * tv; A[5] += s5 * tv;                   \
            A[6] += s6 * tv; A[7] += s7 * tv; A[8] += s8 * tv;                   \
        }                                                                        \
    }

// Layer-0 node kernel: gather A, q; emit layer-1 inputs + nodeE0 directly.
// Up to 4 batch records preloaded as independent loads (nb is SGPR ->
// wave-uniform branches) to collapse the serial record->src->h1 chain.
__global__ __launch_bounds__(256) void k_node0(const int* __restrict__ atom_types) {
    int t = threadIdx.x;
    int node = blockIdx.x * 4 + (t >> 6);
    int lane = t & 63;
    int boff = __builtin_amdgcn_readfirstlane(g_offs[node]);
    int nb = (__builtin_amdgcn_readfirstlane(g_deg[node]) + 7) >> 3;
    const float* __restrict__ hsrc = g_h1a;
    float A[9];
#pragma unroll
    for (int m = 0; m < 9; m++) A[m] = 0.0f;
    float4 rec[4];
#pragma unroll
    for (int b = 0; b < 4; b++) {
        rec[b] = make_float4(0.f, 0.f, 0.f, 0.f);
        if (b < nb && lane < 24)
            rec[b] = *(const float4*)(g_shc + ((size_t)boff + (size_t)b * 8) * 12 + (size_t)lane * 4);
    }
#pragma unroll
    for (int b = 0; b < 4; b++)
        if (b < nb) PROCESS_BATCH(rec[b], (size_t)boff + (size_t)b * 8);
    for (int b = 4; b < nb; b++) {
        size_t j0 = (size_t)boff + (size_t)b * 8;
        float4 rc = make_float4(0.f, 0.f, 0.f, 0.f);
        if (lane < 24) rc = *(const float4*)(g_shc + j0 * 12 + (size_t)lane * 4);
        PROCESS_BATCH(rc, j0);
    }
    const float invn = 1.0f / 16.0f;  // AVG_NEI
    float q = A[0] * invn;
#pragma unroll
    for (int m = 0; m < 9; m++) {
        float a = A[m] * invn;
        q += a * a;
    }
    int type = __builtin_amdgcn_readfirstlane(atom_types[node]);
    float h1n = g_T1[type * 64 + lane];
    float hscn = g_T2[type * 64 + lane];
#pragma unroll
    for (int k = 0; k < 64; k++) {
        float qk = __shfl(q, k, 64);
        h1n += qk * g_M12[k * 128 + lane];
        hscn += qk * g_M12[k * 128 + 64 + lane];
    }
    g_h1b[node * 64 + lane] = h1n;
    g_hscb[node * 64 + lane] = hscn;
    float v = q * g_wp0ro[lane];
#pragma unroll
    for (int off = 32; off > 0; off >>= 1) v += __shfl_down(v, off, 64);
    if (lane == 0) g_nodeE[0][node] = v + g_t0[type];
}

// Layer-1: node_e = q.(Wp1@wro1) + hscb.wro1 — no matvec, no h store.
__global__ __launch_bounds__(256) void k_node1(const float* __restrict__ wro) {
    int t = threadIdx.x;
    int node = blockIdx.x * 4 + (t >> 6);
    int lane = t & 63;
    int boff = __builtin_amdgcn_readfirstlane(g_offs[node]);
    int nb = (__builtin_amdgcn_readfirstlane(g_deg[node]) + 7) >> 3;
    const float* __restrict__ hsrc = g_h1b;
    float A[9];
#pragma unroll
    for (int m = 0; m < 9; m++) A[m] = 0.0f;
    float4 rec[4];
#pragma unroll
    for (int b = 0; b < 4; b++) {
        rec[b] = make_float4(0.f, 0.f, 0.f, 0.f);
        if (b < nb && lane < 24)
            rec[b] = *(const float4*)(g_shc + ((size_t)boff + (size_t)b * 8) * 12 + (size_t)lane * 4);
    }
#pragma unroll
    for (int b = 0; b < 4; b++)
        if (b < nb) PROCESS_BATCH(rec[b], (size_t)boff + (size_t)b * 8);
    for (int b = 4; b < nb; b++) {
        size_t j0 = (size_t)boff + (size_t)b * 8;
        float4 rc = make_float4(0.f, 0.f, 0.f, 0.f);
        if (lane < 24) rc = *(const float4*)(g_shc + j0 * 12 + (size_t)lane * 4);
        PROCESS_BATCH(rc, j0);
    }
    const float invn = 1.0f / 16.0f;  // AVG_NEI
    float q = A[0] * invn;
#pragma unroll
    for (int m = 0; m < 9; m++) {
        float a = A[m] * invn;
        q += a * a;
    }
    float v = q * g_wpro[lane] + g_hscb[node * 64 + lane] * wro[lane];
#pragma unroll
    for (int off = 32; off > 0; off >>= 1) v += __shfl_down(v, off, 64);
    if (lane == 0) g_nodeE[1][node] = v;
}

// One wave per graph; batch is sorted -> binary-search the node range,
// coalesced reduce, single plain store. Zero atomics.
__global__ __launch_bounds__(64) void k_energy(const int* __restrict__ batch,
                                               float* __restrict__ out) {
    int g = blockIdx.x;
    int lane = threadIdx.x;
    int a = 0, b = Nn;
    while (a < b) { int m = (a + b) >> 1; if (batch[m] < g) a = m + 1; else b = m; }
    int st = a;
    b = Nn;
    while (a < b) { int m = (a + b) >> 1; if (batch[m] < g + 1) a = m + 1; else b = m; }
    int en = a;
    float s = 0.0f;
    for (int i = st + lane; i < en; i += 64) s += g_nodeE[0][i] + g_nodeE[1][i];
#pragma unroll
    for (int off = 32; off > 0; off >>= 1) s += __shfl_down(s, off, 64);
    if (lane == 0) out[g] = s;
}

extern "C" void kernel_launch(void* const* d_in, const int* in_sizes, int n_in,
                              void* d_out, int out_size, void* d_ws, size_t ws_size,
                              hipStream_t stream) {
    const float* pos     = (const float*)d_in[0];
    const float* W_embed = (const float*)d_in[1];
    const float* W_r1    = (const float*)d_in[2];
    const float* b_r1    = (const float*)d_in[3];
    const float* W_r2    = (const float*)d_in[4];
    const float* W_up    = (const float*)d_in[5];
    const float* W_sc    = (const float*)d_in[6];
    const float* W_prod  = (const float*)d_in[7];
    const float* w_ro    = (const float*)d_in[8];
    const int* atom_types = (const int*)d_in[9];
    const int* eidx       = (const int*)d_in[10];
    const int* batch      = (const int*)d_in[11];
    float* out = (float*)d_out;

    k_init<<<17 + EDGEBLK, 256, 0, stream>>>(W_r1, W_embed, W_up, W_sc, W_prod, w_ro, out, out_size);
    k_deg<<<Ee / 256, 256, 0, stream>>>(eidx);
    k_scan<<<1, 1024, 0, stream>>>();
    k_fill<<<Ee / 256, 256, 0, stream>>>(eidx);
    k_edge<<<EDGEBLK + (Nn * 64 + 511) / 512, 512, 0, stream>>>(pos, b_r1, W_r2, atom_types);
    k_node0<<<Nn / 4, 256, 0, stream>>>(atom_types);
    k_node1<<<Nn / 4, 256, 0, stream>>>(w_ro + 64);
    k_energy<<<Gg, 64, 0, stream>>>(batch, out);
}

// Round 17
// 221.220 us; speedup vs baseline: 1.4087x; 1.0232x over previous
//
#include <hip/hip_runtime.h>
#include <hip/hip_fp16.h>
#include <math.h>

#define Nn 10000
#define Ee 160000
#define NBb 8
#define Gg 100
#define NT 5
#define CSRMAX 230400            // >= Ee + 7*Nn, multiple of 256
#define EDGEBLK (CSRMAX / 256)   // 900

// sh record per slot: [0..3]=sh0..3, [4..7]=sh4..7, [8]=sh8, [9]=src bits, [10,11]=0
__device__ __align__(16) float g_shc[(size_t)CSRMAX * 12];
// R in fp16, slot-pair interleaved: g_R2[pair*64 + chan] = (R[2p][c], R[2p+1][c])
__device__ __align__(16) __half2 g_R2[(size_t)(CSRMAX / 2) * 64];
__device__ float g_h1a[Nn * 64];   // layer-0 h@Wup0 (= E1[type])
__device__ float g_h1b[Nn * 64];   // layer-1 h'@Wup1
__device__ float g_hscb[Nn * 64];  // layer-1 h'@Wsc1
__device__ float g_nodeE[2][Nn];   // per-layer node energies (no atomics)
__device__ int   g_deg[Nn];
__device__ int   g_offs[Nn + 1];
__device__ int   g_cursor[Nn];
__device__ int2  g_er[CSRMAX];     // per-slot (sender, receiver); .x=-1 for pads
// precomputed algebra (k_init)
__device__ float g_W1T[64 * NBb];  // W_r1 transposed: [j][k]
__device__ float g_E1[NT * 64];    // Wembed@Wup0
__device__ float g_Esc[NT * 64];   // Wembed@Wsc0 (scratch)
__device__ float g_T1[NT * 64];    // Esc@Wup1
__device__ float g_T2[NT * 64];    // Esc@Wsc1
__device__ float g_M12[64 * 128];  // [k][0:64]=Wp0@Wup1 row, [k][64:128]=Wp0@Wsc1 row
__device__ float g_wp0ro[64];      // Wp0@wro0
__device__ float g_wpro[64];       // Wp1@wro1
__device__ float g_t0[NT];         // Esc@wro0

// Fused: blocks 0-16 precompute algebra tables; blocks 17.. zero/init state.
__global__ __launch_bounds__(256) void k_init(const float* __restrict__ Wr1,
                                              const float* __restrict__ Wembed,
                                              const float* __restrict__ Wup,
                                              const float* __restrict__ Wsc,
                                              const float* __restrict__ Wprod,
                                              const float* __restrict__ wro,
                                              float* __restrict__ out, int out_size) {
    int t = threadIdx.x;
    int b = blockIdx.x;
    if (b >= 17) {
        int i = (b - 17) * 256 + t;
        if (i < CSRMAX) g_er[i].x = -1;
        if (i < out_size) out[i] = 0.0f;
        if (i < Nn) { g_deg[i] = 0; g_cursor[i] = 0; }
        return;
    }
    if (b == 0) {
        for (int i = t; i < 64 * NBb; i += 256) {
            int k = i >> 6, j = i & 63;  // Wr1[k][j]
            g_W1T[j * NBb + k] = Wr1[i];
        }
        for (int i = t; i < NT * 64; i += 256) {
            int g = i >> 6, c = i & 63;
            float s1 = 0.f, s2 = 0.f;
            for (int j = 0; j < 64; j++) {
                float w = Wembed[g * 64 + j];
                s1 += w * Wup[j * 64 + c];
                s2 += w * Wsc[j * 64 + c];
            }
            g_E1[i] = s1; g_Esc[i] = s2;
        }
        if (t < 64) {
            float s1 = 0.f, s2 = 0.f;
            for (int c = 0; c < 64; c++) {
                s1 += Wprod[t * 64 + c] * wro[c];
                s2 += Wprod[4096 + t * 64 + c] * wro[64 + c];
            }
            g_wp0ro[t] = s1; g_wpro[t] = s2;
        }
        __syncthreads();
        for (int i = t; i < NT * 64; i += 256) {
            int g = i >> 6, c = i & 63;
            float s1 = 0.f, s2 = 0.f;
            for (int j = 0; j < 64; j++) {
                float w = g_Esc[g * 64 + j];
                s1 += w * Wup[4096 + j * 64 + c];
                s2 += w * Wsc[4096 + j * 64 + c];
            }
            g_T1[i] = s1; g_T2[i] = s2;
        }
        if (t < NT) {
            float s = 0.f;
            for (int j = 0; j < 64; j++) s += g_Esc[t * 64 + j] * wro[j];
            g_t0[t] = s;
        }
    } else {
        int idx = (b - 1) * 256 + t;          // 0..4095
        int k = idx >> 6, c = idx & 63;
        float s1 = 0.f, s2 = 0.f;
        for (int j = 0; j < 64; j++) {
            float w = Wprod[k * 64 + j];       // wave-uniform -> scalar
            s1 += w * Wup[4096 + j * 64 + c];
            s2 += w * Wsc[4096 + j * 64 + c];
        }
        g_M12[k * 128 + c] = s1;
        g_M12[k * 128 + 64 + c] = s2;
    }
}

__global__ __launch_bounds__(256) void k_deg(const int* __restrict__ eidx) {
    int e = blockIdx.x * 256 + threadIdx.x;
    if (e < Ee) atomicAdd(&g_deg[eidx[Ee + e]], 1);
}

// prefix sum of degrees padded up to multiples of 8
__global__ __launch_bounds__(1024) void k_scan() {
    __shared__ int part[1024];
    int t = threadIdx.x;
    const int CH = (Nn + 1023) / 1024;  // 10
    int st = t * CH;
    int en = st + CH; if (en > Nn) en = Nn;
    int s = 0;
    for (int i = st; i < en; i++) s += (g_deg[i] + 7) & ~7;
    part[t] = s;
    __syncthreads();
    for (int d = 1; d < 1024; d <<= 1) {
        int v = (t >= d) ? part[t - d] : 0;
        __syncthreads();
        part[t] += v;
        __syncthreads();
    }
    int base = (t == 0) ? 0 : part[t - 1];
    for (int i = st; i < en; i++) { g_offs[i] = base; base += (g_deg[i] + 7) & ~7; }
    if (t == 1023) g_offs[Nn] = part[1023];
}

__global__ __launch_bounds__(256) void k_fill(const int* __restrict__ eidx) {
    int e = blockIdx.x * 256 + threadIdx.x;
    if (e >= Ee) return;
    int snd = eidx[e];
    int r = eidx[Ee + e];
    int p = g_offs[r] + atomicAdd(&g_cursor[r], 1);
    g_er[p] = make_int2(snd, r);
}

// Blocks < EDGEBLK: edge MLP (512 thr; chalf pinned to SGPR — compiler-visible
// uniformity keeps weights on the scalar path; r11/r13 taught this).
// Blocks >= EDGEBLK: h1a init. R stored fp16, slot-pair interleaved.
__global__ __launch_bounds__(512) void k_edge(const float* __restrict__ pos,
                                              const float* __restrict__ br1,
                                              const float* __restrict__ Wr2,
                                              const int* __restrict__ atom_types) {
    int t = threadIdx.x;
    if (blockIdx.x >= EDGEBLK) {
        int i = (blockIdx.x - EDGEBLK) * 512 + t;
        if (i < Nn * 64) {
            int n = i >> 6, c = i & 63;
            g_h1a[i] = g_E1[atom_types[n] * 64 + c];
        }
        return;
    }
    __shared__ float sT[32][257];
    int total = g_offs[Nn];
    if (blockIdx.x * 256 >= total) return;
    int slot = t & 255;
    int chalf = __builtin_amdgcn_readfirstlane(t >> 8);   // force SGPR
    int s = blockIdx.x * 256 + slot;
    int2 er = g_er[s];
    bool real = (er.x >= 0);
    int snd = real ? er.x : 0;
    int rcv = real ? er.y : 0;

    float vx = pos[3 * rcv + 0] - pos[3 * snd + 0];
    float vy = pos[3 * rcv + 1] - pos[3 * snd + 1];
    float vz = pos[3 * rcv + 2] - pos[3 * snd + 2];
    float r = sqrtf(vx * vx + vy * vy + vz * vz);
    float inv = __builtin_amdgcn_rcpf(fmaxf(r, 1e-9f));
    float x = vx * inv, y = vy * inv, z = vz * inv;
    const float s3 = 1.7320508f;
    if (chalf == 0) {
        float4* shp = (float4*)(g_shc + (size_t)s * 12);
        if (real) {
            shp[0] = make_float4(1.0f, x, y, z);
            shp[1] = make_float4(s3 * x * y, s3 * y * z, 0.5f * (3.0f * z * z - 1.0f), s3 * x * z);
            shp[2] = make_float4(0.5f * s3 * (x * x - y * y), __int_as_float(snd), 0.f, 0.f);
        } else {
            shp[0] = make_float4(0.f, 0.f, 0.f, 0.f);
            shp[1] = make_float4(0.f, 0.f, 0.f, 0.f);
            shp[2] = make_float4(0.f, 0.f, 0.f, 0.f);
        }
    }

    float xx = r * 0.2f;
    float env = 0.0f;
    if (xx < 1.0f) {
        float x2 = xx * xx;
        float x6 = x2 * x2 * x2;
        float x7 = x6 * xx;
        float x8 = x7 * xx;
        env = 1.0f - 28.0f * x6 + 48.0f * x7 - 21.0f * x8;
    }
    const float pref = 0.63245553f;  // sqrt(2/R_MAX)
    const float PI_F = 3.14159265358979f;
    float fac = pref * inv * env;
    float ef[NBb];
#pragma unroll
    for (int k = 0; k < NBb; k++)
        ef[k] = fac * __sinf((float)(k + 1) * PI_F * r * 0.2f);

    float acc[32];
#pragma unroll
    for (int c = 0; c < 32; c++) acc[c] = 0.0f;
    const float* __restrict__ w2base = Wr2 + chalf * 32;   // SGPR offset
    for (int j = 0; j < 64; j++) {
        float a = br1[j];
#pragma unroll
        for (int k = 0; k < NBb; k++) a += ef[k] * g_W1T[j * NBb + k];
        a = a * __builtin_amdgcn_rcpf(1.0f + __expf(-a));
        const float* __restrict__ w2 = w2base + j * 64;
#pragma unroll
        for (int c = 0; c < 32; c++) acc[c] += a * w2[c];
    }

    size_t baseP = (size_t)blockIdx.x * 128;   // pair base
#pragma unroll
    for (int chunk = 0; chunk < 2; chunk++) {
        if (chalf == chunk) {
#pragma unroll
            for (int c = 0; c < 32; c++) sT[c][slot] = real ? acc[c] : 0.0f;
        }
        __syncthreads();
        // 512 threads x 8 half2 (16B) = 128 pairs x 32 chans for this chunk
        {
            int p = t >> 2;      // 0..127
            int cg = t & 3;      // 0..3
            __half2 out8[8];
#pragma unroll
            for (int j = 0; j < 8; j++) {
                int c = cg * 8 + j;
                out8[j] = __floats2half2_rn(sT[c][2 * p], sT[c][2 * p + 1]);
            }
            __half2* dst = g_R2 + (baseP + p) * 64 + chunk * 32 + cg * 8;
            *(uint4*)dst = *(uint4*)out8;
        }
        __syncthreads();
    }
}

#define PROCESS_BATCH(rec, j0)                                                   \
    {                                                                            \
        __half2 r2[4];                                                           \
        _Pragma("unroll")                                                        \
        for (int kk = 0; kk < 4; kk++)                                           \
            r2[kk] = g_R2[((j0) / 2 + kk) * 64 + lane];                          \
        _Pragma("unroll")                                                        \
        for (int k = 0; k < 8; k++) {                                            \
            float s0 = __shfl(rec.x, 3 * k, 64), s1 = __shfl(rec.y, 3 * k, 64);  \
            float s2 = __shfl(rec.z, 3 * k, 64), s3 = __shfl(rec.w, 3 * k, 64);  \
            float s4 = __shfl(rec.x, 3 * k + 1, 64), s5 = __shfl(rec.y, 3 * k + 1, 64); \
            float s6 = __shfl(rec.z, 3 * k + 1, 64), s7 = __shfl(rec.w, 3 * k + 1, 64); \
            float s8 = __shfl(rec.x, 3 * k + 2, 64);                             \
            int src = __float_as_int(__shfl(rec.y, 3 * k + 2, 64));              \
            float rv = (k & 1) ? __high2float(r2[k >> 1]) : __low2float(r2[k >> 1]); \
            float tv = rv * hsrc[(size_t)src * 64 + lane];                       \
            A[0] += s0 * tv; A[1] += s1 * tv; A[2] += s2 * tv;                   \
            A[3] += s3 * tv; A[4] += s4 * tv; A[5] += s5 * tv;                   \
            A[6] += s6 * tv; A[7] += s7 * tv; A[8] += s8 * tv;                   \
        }                                                                        \
    }

// Layer-0 node kernel: gather A, q; emit layer-1 inputs + nodeE0 directly.
__global__ __launch_bounds__(256) void k_node0(const int* __restrict__ atom_types) {
    int t = threadIdx.x;
    int node = blockIdx.x * 4 + (t >> 6);
    int lane = t & 63;
    int boff = __builtin_amdgcn_readfirstlane(g_offs[node]);
    int nb = (__builtin_amdgcn_readfirstlane(g_deg[node]) + 7) >> 3;
    const float* __restrict__ hsrc = g_h1a;
    float A[9];
#pragma unroll
    for (int m = 0; m < 9; m++) A[m] = 0.0f;
    float4 rec[4];
#pragma unroll
    for (int b = 0; b < 4; b++) {
        rec[b] = make_float4(0.f, 0.f, 0.f, 0.f);
        if (b < nb && lane < 24)
            rec[b] = *(const float4*)(g_shc + ((size_t)boff + (size_t)b * 8) * 12 + (size_t)lane * 4);
    }
#pragma unroll
    for (int b = 0; b < 4; b++)
        if (b < nb) PROCESS_BATCH(rec[b], ((size_t)boff + (size_t)b * 8));
    for (int b = 4; b < nb; b++) {
        size_t j0 = (size_t)boff + (size_t)b * 8;
        float4 rc = make_float4(0.f, 0.f, 0.f, 0.f);
        if (lane < 24) rc = *(const float4*)(g_shc + j0 * 12 + (size_t)lane * 4);
        PROCESS_BATCH(rc, j0);
    }
    const float invn = 1.0f / 16.0f;  // AVG_NEI
    float q = A[0] * invn;
#pragma unroll
    for (int m = 0; m < 9; m++) {
        float a = A[m] * invn;
        q += a * a;
    }
    int type = __builtin_amdgcn_readfirstlane(atom_types[node]);
    float h1n = g_T1[type * 64 + lane];
    float hscn = g_T2[type * 64 + lane];
#pragma unroll
    for (int k = 0; k < 64; k++) {
        float qk = __shfl(q, k, 64);
        h1n += qk * g_M12[k * 128 + lane];
        hscn += qk * g_M12[k * 128 + 64 + lane];
    }
    g_h1b[node * 64 + lane] = h1n;
    g_hscb[node * 64 + lane] = hscn;
    float v = q * g_wp0ro[lane];
#pragma unroll
    for (int off = 32; off > 0; off >>= 1) v += __shfl_down(v, off, 64);
    if (lane == 0) g_nodeE[0][node] = v + g_t0[type];
}

// Layer-1: node_e = q.(Wp1@wro1) + hscb.wro1 — no matvec, no h store.
__global__ __launch_bounds__(256) void k_node1(const float* __restrict__ wro) {
    int t = threadIdx.x;
    int node = blockIdx.x * 4 + (t >> 6);
    int lane = t & 63;
    int boff = __builtin_amdgcn_readfirstlane(g_offs[node]);
    int nb = (__builtin_amdgcn_readfirstlane(g_deg[node]) + 7) >> 3;
    const float* __restrict__ hsrc = g_h1b;
    float A[9];
#pragma unroll
    for (int m = 0; m < 9; m++) A[m] = 0.0f;
    float4 rec[4];
#pragma unroll
    for (int b = 0; b < 4; b++) {
        rec[b] = make_float4(0.f, 0.f, 0.f, 0.f);
        if (b < nb && lane < 24)
            rec[b] = *(const float4*)(g_shc + ((size_t)boff + (size_t)b * 8) * 12 + (size_t)lane * 4);
    }
#pragma unroll
    for (int b = 0; b < 4; b++)
        if (b < nb) PROCESS_BATCH(rec[b], ((size_t)boff + (size_t)b * 8));
    for (int b = 4; b < nb; b++) {
        size_t j0 = (size_t)boff + (size_t)b * 8;
        float4 rc = make_float4(0.f, 0.f, 0.f, 0.f);
        if (lane < 24) rc = *(const float4*)(g_shc + j0 * 12 + (size_t)lane * 4);
        PROCESS_BATCH(rc, j0);
    }
    const float invn = 1.0f / 16.0f;  // AVG_NEI
    float q = A[0] * invn;
#pragma unroll
    for (int m = 0; m < 9; m++) {
        float a = A[m] * invn;
        q += a * a;
    }
    float v = q * g_wpro[lane] + g_hscb[node * 64 + lane] * wro[lane];
#pragma unroll
    for (int off = 32; off > 0; off >>= 1) v += __shfl_down(v, off, 64);
    if (lane == 0) g_nodeE[1][node] = v;
}

// One wave per graph; batch is sorted -> binary-search the node range,
// coalesced reduce, single plain store. Zero atomics.
__global__ __launch_bounds__(64) void k_energy(const int* __restrict__ batch,
                                               float* __restrict__ out) {
    int g = blockIdx.x;
    int lane = threadIdx.x;
    int a = 0, b = Nn;
    while (a < b) { int m = (a + b) >> 1; if (batch[m] < g) a = m + 1; else b = m; }
    int st = a;
    b = Nn;
    while (a < b) { int m = (a + b) >> 1; if (batch[m] < g + 1) a = m + 1; else b = m; }
    int en = a;
    float s = 0.0f;
    for (int i = st + lane; i < en; i += 64) s += g_nodeE[0][i] + g_nodeE[1][i];
#pragma unroll
    for (int off = 32; off > 0; off >>= 1) s += __shfl_down(s, off, 64);
    if (lane == 0) out[g] = s;
}

extern "C" void kernel_launch(void* const* d_in, const int* in_sizes, int n_in,
                              void* d_out, int out_size, void* d_ws, size_t ws_size,
                              hipStream_t stream) {
    const float* pos     = (const float*)d_in[0];
    const float* W_embed = (const float*)d_in[1];
    const float* W_r1    = (const float*)d_in[2];
    const float* b_r1    = (const float*)d_in[3];
    const float* W_r2    = (const float*)d_in[4];
    const float* W_up    = (const float*)d_in[5];
    const float* W_sc    = (const float*)d_in[6];
    const float* W_prod  = (const float*)d_in[7];
    const float* w_ro    = (const float*)d_in[8];
    const int* atom_types = (const int*)d_in[9];
    const int* eidx       = (const int*)d_in[10];
    const int* batch      = (const int*)d_in[11];
    float* out = (float*)d_out;

    k_init<<<17 + EDGEBLK, 256, 0, stream>>>(W_r1, W_embed, W_up, W_sc, W_prod, w_ro, out, out_size);
    k_deg<<<Ee / 256, 256, 0, stream>>>(eidx);
    k_scan<<<1, 1024, 0, stream>>>();
    k_fill<<<Ee / 256, 256, 0, stream>>>(eidx);
    k_edge<<<EDGEBLK + (Nn * 64 + 511) / 512, 512, 0, stream>>>(pos, b_r1, W_r2, atom_types);
    k_node0<<<Nn / 4, 256, 0, stream>>>(atom_types);
    k_node1<<<Nn / 4, 256, 0, stream>>>(w_ro + 64);
    k_energy<<<Gg, 64, 0, stream>>>(batch, out);
}